// Round 16
// baseline (686.990 us; speedup 1.0000x reference)
//
#include <hip/hip_runtime.h>
#include <stdint.h>

#define NN    6000
#define KNNC  10
#define MM    (NN * 2 * (KNNC + 1))   // 132000
#define DD    (2 * NN)                // 12000
#define LCH   3                       // hidden layers (LC-1)
#define BLK   256

// One MLP wave (64 rows) per block -> ceil(132000/64) = 2063 blocks.
#define FBLOCKS ((MM + 63) / 64)      // 2063
#define NV      ((long long)DD * DD / 4)   // 36,000,000 float4s
#define SCGRID  ((MM + BLK - 1) / BLK)     // 516

// Round-16: R1's kernel verbatim + native-atomic scatter. The R15 result
// (scatter-kill = no change) closed the component system: unsafe scatter
// ~22us, memset 94us, MLP ~158us IMPLEMENTATION-INVARIANT (VALU/MFMA,
// s_load/LDS, any occupancy), fill_place ~113us. The one unexploited
// directly-measured fact: R1's wave-specialized fused fill+MLP = 188us
// (689 - 375 poison - 126 CAS-scatter, CAS anchored by R2's direct 379/880)
// -- ~66us of real overlap vs the 94+160 sequential sum, because wave-spec
// guarantees fill/MLP co-residency per CU (block-spec R11 overlapped ZERO:
// 253 ~= 94+160). R1's only flaw was its CAS scatter; R4 swapped to native
// atomics but simultaneously de-fused (two changes), mis-crediting the
// gain. This round = R1 fused (byte-identical structure) + unsafeAtomicAdd
// scatter. Predicted 575-615.
__global__ __launch_bounds__(BLK) void fused_mlp_zero(
    const float* __restrict__ CK,    // [MM,3]
    const float* __restrict__ Win,   // [3,64]
    const float* __restrict__ bin,   // [64]
    const float* __restrict__ Whid,  // [3,64,64]
    const float* __restrict__ bhid,  // [3,64]
    const float* __restrict__ Wout,  // [64,4]
    const float* __restrict__ bout,  // [4]
    float* __restrict__ vals,        // [MM,2] (workspace)
    float* __restrict__ out)         // [DD*DD], zero-filled here
{
    __shared__ float sH[64 * 64];    // activations, layout [k][lane], 16 KiB

    const int tid  = threadIdx.x;
    const int wave = tid >> 6;
    const int lane = tid & 63;
    const int mlpw = blockIdx.x & 3;          // rotate MLP wave slot across SIMDs

    if (wave != mlpw) {
        // ---- fill specialization: 3 waves per block ----
        const int fw = wave - (wave > mlpw ? 1 : 0);       // 0..2
        const long long ft = (long long)blockIdx.x * 192 + fw * 64 + lane;
        const long long stride = (long long)FBLOCKS * 192;
        float4 z = make_float4(0.f, 0.f, 0.f, 0.f);
        float4* outv = (float4*)out;
        for (long long i = ft; i < NV; i += stride) outv[i] = z;
        return;
    }

    // ---- MLP specialization: one row per lane ----
    const int m = blockIdx.x * 64 + lane;
    if (m >= MM) return;

    const float x0 = CK[m * 3 + 0];
    const float x1 = CK[m * 3 + 1];
    const float x2 = CK[m * 3 + 2];

    float* __restrict__ hcol = sH + lane;     // h[k] lives at hcol[k*64]

    // Input layer 3 -> 64; weight/bias reads wave-uniform (broadcast).
#pragma unroll
    for (int j = 0; j < 64; j++) {
        float a = bin[j];
        a = fmaf(x0, Win[j],       a);
        a = fmaf(x1, Win[64 + j],  a);
        a = fmaf(x2, Win[128 + j], a);
        hcol[j * 64] = fmaxf(a, 0.0f);        // static addr: ds_write_b32
    }

    // Hidden layers: g_j = sum_k W[k][j] * h_k (row-major W matches h @ W).
    // Same-wave DS ordering -> no barriers; k-loop unroll x8 batches the
    // wave-uniform weight loads ahead of the FMAs.
#pragma unroll 1
    for (int l = 0; l < LCH; l++) {
        const float4* __restrict__ W4 = (const float4*)(Whid + (l << 12));
        const float*  __restrict__ bh = bhid + (l << 6);
        float g[64];
#pragma unroll
        for (int j = 0; j < 64; j++) g[j] = bh[j];
#pragma unroll 8
        for (int k = 0; k < 64; k++) {
            const float hk = hcol[k * 64];    // ds_read_b32 (2-way alias: free)
            const float4* __restrict__ Wk = W4 + (k << 4);   // row k: 16 float4s
#pragma unroll
            for (int j4 = 0; j4 < 16; j4++) {
                float4 w = Wk[j4];
                g[j4 * 4 + 0] = fmaf(w.x, hk, g[j4 * 4 + 0]);
                g[j4 * 4 + 1] = fmaf(w.y, hk, g[j4 * 4 + 1]);
                g[j4 * 4 + 2] = fmaf(w.z, hk, g[j4 * 4 + 2]);
                g[j4 * 4 + 3] = fmaf(w.w, hk, g[j4 * 4 + 3]);
            }
        }
#pragma unroll
        for (int j = 0; j < 64; j++) hcol[j * 64] = fmaxf(g[j], 0.0f);
    }

    // Output layer collapsed over mi: vals[:,mj] = C[:,mj] + C[:,mj+2]
    float v0 = bout[0] + bout[2];
    float v1 = bout[1] + bout[3];
#pragma unroll 8
    for (int k = 0; k < 64; k++) {
        float4 wo = *((const float4*)Wout + k);
        const float hk = hcol[k * 64];
        v0 = fmaf(hk, wo.x + wo.z, v0);
        v1 = fmaf(hk, wo.y + wo.w, v1);
    }
    *(float2*)(vals + 2 * m) = make_float2(v0, v1);
}

__global__ __launch_bounds__(BLK) void scatter_add(
    const float* __restrict__ vals,   // [MM,2]
    const int* __restrict__ coo,      // [2,MM]
    float* __restrict__ out)          // [DD*DD]
{
    const int t = blockIdx.x * BLK + threadIdx.x;
    if (t >= MM) return;
    const int r2 = coo[t] * 2;        // row index * MODES
    const int c2 = coo[MM + t] * 2;   // col index * MODES
    const float2 v = *(const float2*)(vals + 2 * t);
    // mj=0: element (r2, c2); mj=1: element (r2+1, c2+1) = +DD+1 flat
    const long long f0 = (long long)r2 * DD + c2;
    // Native global_atomic_add_f32 (fire-and-forget), ~22us for 264k lines
    // (R9/R15 equation system), vs 126us for the plain-atomicAdd CAS loop
    // (R2 direct anchor).
    unsafeAtomicAdd(out + f0, v.x);
    unsafeAtomicAdd(out + f0 + DD + 1, v.y);
}

extern "C" void kernel_launch(void* const* d_in, const int* in_sizes, int n_in,
                              void* d_out, int out_size, void* d_ws, size_t ws_size,
                              hipStream_t stream) {
    const float* CK   = (const float*)d_in[0];
    const float* Win  = (const float*)d_in[1];
    const float* bin  = (const float*)d_in[2];
    const float* Whid = (const float*)d_in[3];
    const float* bhid = (const float*)d_in[4];
    const float* Wout = (const float*)d_in[5];
    const float* bout = (const float*)d_in[6];
    const int* coo    = (const int*)d_in[7];
    float* out        = (float*)d_out;
    float* vals       = (float*)d_ws;

    fused_mlp_zero<<<FBLOCKS, BLK, 0, stream>>>(
        CK, Win, bin, Whid, bhid, Wout, bout, vals, out);
    scatter_add<<<SCGRID, BLK, 0, stream>>>(vals, coo, out);
}

// Round 17
// 665.179 us; speedup vs baseline: 1.0328x; 1.0328x over previous
//
#include <hip/hip_runtime.h>
#include <stdint.h>

#define NN    6000
#define KNNC  10
#define MM    (NN * 2 * (KNNC + 1))   // 132000
#define DD    (2 * NN)                // 12000
#define LCH   3                       // hidden layers (LC-1)
#define BLK   256

#define RB     128                     // rows per MLP block
#define RPL    2                       // rows per lane
#define MLPGRID ((MM + RB - 1) / RB)   // 1032
#define SCGRID  ((MM + BLK - 1) / BLK) // 516 (fallback)
#define OUTBYTES ((size_t)DD * DD * 4) // 576,000,000

#define MAXB     128                   // bucket capacity (avg 22, max ~45; R15-proven)
#define VALS_B   (MM * 2 * 4)          // 1,056,000
#define CNT_B    (NN * 4)              // 24,000
#define BINS_B   (NN * MAXB * 4)       // 3,072,000
#define WS_NEEDED (VALS_B + CNT_B + BINS_B)   // 4,152,000

// Round-17. R16 (R1-fused + native atomics, 687) vs R1 (same fused + plain
// atomics, 689) is a controlled pair: the atomics swap = 0 -> plain
// atomicAdd(f32) already lowered native, R4's "-100 from atomics" was never
// real. Re-solving all 15 rounds with one scatter constant: scatter ~125us
// (DRAM row-activate bound: 264k random 64B lines), memset 94, MLP(R9
// s_load body) 55, MLP(64KB-LDS) 149, MLP(mfma) 71, R1-fused 188
// (R16 reproduced 187). The pig is the fill+scatter pair (219us).
// Fix: fill_patch - each block owns ONE output row: stream 48KB zeros (no
// LDS, max occupancy, full store BW), __syncthreads (gfx950 emits
// s_waitcnt vmcnt(0) before s_barrier -> stores are in L2, the coherence
// point), then unsafeAtomicAdd its ~22 binned entries into the still-
// L2-resident lines (~3MB in flight/XCD < 4MB L2) -> no DRAM activates.
// Rows are block-exclusive -> no race with the zeroing. mlp_bin/zero_cnt
// byte-identical to R15 (correctness-proven incl. MAXB occupancy).

__global__ void zero_cnt(int* __restrict__ cnt) {
    const int i = blockIdx.x * BLK + threadIdx.x;
    if (i < NN) cnt[i] = 0;
}

__global__ __launch_bounds__(BLK, 4) void mlp_bin(
    const float* __restrict__ CK,    // [MM,3]
    const float* __restrict__ Win,   // [3,64]
    const float* __restrict__ bin,   // [64]
    const float* __restrict__ Whid,  // [3,64,64]
    const float* __restrict__ bhid,  // [3,64]
    const float* __restrict__ Wout,  // [64,4]
    const float* __restrict__ bout,  // [4]
    const int* __restrict__ coo,     // [2,MM]
    float* __restrict__ vals,        // [MM,2]
    int* __restrict__ cnt,           // [NN] (pre-zeroed) or null
    int* __restrict__ bins,          // [NN,MAXB] or null
    const int do_bins)
{
    __shared__ float sH[64 * RB];    // activations [k][row], row=lane*2+r, 32 KiB

    const int tid  = threadIdx.x;
    const int wave = tid >> 6;
    const int lane = tid & 63;
    // Wave-uniform channel offset in an SGPR -> weight loads scalarize.
    const int jo = __builtin_amdgcn_readfirstlane((tid >> 6) << 4);

    const int rbase = blockIdx.x * RB;
    const int mb0   = rbase + lane * 2;        // lane's first row (even)
    const int mb    = mb0 < MM ? mb0 : MM - 2; // clamp loads, guard stores

    // Lane's 2 rows of inputs: 6 consecutive floats -> 3 float2.
    const float2 ca = *(const float2*)(CK + mb * 3);      // x0r0 x1r0
    const float2 cb = *(const float2*)(CK + mb * 3 + 2);  // x2r0 x0r1
    const float2 cc = *(const float2*)(CK + mb * 3 + 4);  // x1r1 x2r1
    const float x0[RPL] = {ca.x, cb.y};
    const float x1[RPL] = {ca.y, cc.x};
    const float x2[RPL] = {cb.x, cc.y};

    // Input layer: this wave's 16 channels for its 2 packed rows.
#pragma unroll
    for (int jj = 0; jj < 16; jj++) {
        const int j = jo + jj;
        const float w0 = Win[j], w1 = Win[64 + j], w2 = Win[128 + j];  // s_load
        const float bj = bin[j];
        float2 hv;
        hv.x = fmaxf(fmaf(x2[0], w2, fmaf(x1[0], w1, fmaf(x0[0], w0, bj))), 0.f);
        hv.y = fmaxf(fmaf(x2[1], w2, fmaf(x1[1], w1, fmaf(x0[1], w0, bj))), 0.f);
        *(float2*)(sH + j * RB + lane * 2) = hv;
    }
    __syncthreads();

    // Hidden layers, barrier-lockstep (all waves on the same 16KB W -> K$-hot).
#pragma unroll 1
    for (int l = 0; l < LCH; l++) {
        const float* __restrict__ Wl = Whid + (l << 12) + jo;  // uniform SGPR base
        const float* __restrict__ bh = bhid + (l << 6) + jo;

        float g[RPL][16];
#pragma unroll
        for (int jj = 0; jj < 16; jj++) {
            const float bj = bh[jj];           // s_load
            g[0][jj] = bj;
            g[1][jj] = bj;
        }

#pragma unroll 4
        for (int k = 0; k < 64; k++) {
            // This wave's 16-channel weight slice: 64B uniform -> s_load.
            const float4 wa = *(const float4*)(Wl + (k << 6));
            const float4 wb = *(const float4*)(Wl + (k << 6) + 4);
            const float4 wc = *(const float4*)(Wl + (k << 6) + 8);
            const float4 wd = *(const float4*)(Wl + (k << 6) + 12);
            const float2 hv = *(const float2*)(sH + k * RB + lane * 2);
            const float hk[RPL] = {hv.x, hv.y};
#pragma unroll
            for (int r = 0; r < RPL; r++) {
                g[r][0]  = fmaf(wa.x, hk[r], g[r][0]);
                g[r][1]  = fmaf(wa.y, hk[r], g[r][1]);
                g[r][2]  = fmaf(wa.z, hk[r], g[r][2]);
                g[r][3]  = fmaf(wa.w, hk[r], g[r][3]);
                g[r][4]  = fmaf(wb.x, hk[r], g[r][4]);
                g[r][5]  = fmaf(wb.y, hk[r], g[r][5]);
                g[r][6]  = fmaf(wb.z, hk[r], g[r][6]);
                g[r][7]  = fmaf(wb.w, hk[r], g[r][7]);
                g[r][8]  = fmaf(wc.x, hk[r], g[r][8]);
                g[r][9]  = fmaf(wc.y, hk[r], g[r][9]);
                g[r][10] = fmaf(wc.z, hk[r], g[r][10]);
                g[r][11] = fmaf(wc.w, hk[r], g[r][11]);
                g[r][12] = fmaf(wd.x, hk[r], g[r][12]);
                g[r][13] = fmaf(wd.y, hk[r], g[r][13]);
                g[r][14] = fmaf(wd.z, hk[r], g[r][14]);
                g[r][15] = fmaf(wd.w, hk[r], g[r][15]);
            }
        }
        __syncthreads();   // all reads of sH for layer l complete

        // relu + writeback: 16 b64 (2 packed rows per channel).
#pragma unroll
        for (int jj = 0; jj < 16; jj++) {
            float2 hv;
            hv.x = fmaxf(g[0][jj], 0.f);
            hv.y = fmaxf(g[1][jj], 0.f);
            *(float2*)(sH + (jo + jj) * RB + lane * 2) = hv;
        }
        __syncthreads();   // h ready for next layer / output
    }

    // Output layer collapsed over mi: v[:,mj] = C[:,mj] + C[:,mj+2].
    float v0[RPL], v1[RPL];
    const float b02 = bout[0] + bout[2], b13 = bout[1] + bout[3];
#pragma unroll
    for (int r = 0; r < RPL; r++) { v0[r] = b02; v1[r] = b13; }
#pragma unroll 8
    for (int k = 0; k < 64; k++) {
        const float4 wo = ((const float4*)Wout)[k];     // s_load
        const float wxz = wo.x + wo.z, wyw = wo.y + wo.w;
        const float2 hv = *(const float2*)(sH + k * RB + lane * 2);
        v0[0] = fmaf(hv.x, wxz, v0[0]);  v1[0] = fmaf(hv.x, wyw, v1[0]);
        v0[1] = fmaf(hv.y, wxz, v0[1]);  v1[1] = fmaf(hv.y, wyw, v1[1]);
    }
    if (wave == 0 && mb0 < MM) {
        *(float4*)(vals + 2 * mb0) = make_float4(v0[0], v1[0], v0[1], v1[1]);
        if (do_bins) {
            // Bin both rows by destination row index i = coo0[m].
#pragma unroll
            for (int r = 0; r < RPL; r++) {
                const int m = mb0 + r;
                const int i = coo[m];
                const int pos = atomicAdd(&cnt[i], 1);
                if (pos < MAXB) bins[i * MAXB + pos] = m;
            }
        }
    }
}

// Block b owns output row (2i+mj), i=b>>1, mj=b&1: stream zeros (no LDS,
// full store BW), barrier (drains vmcnt -> stores in L2), then atomically
// patch its ~22 entries into the still-L2-resident lines. No DRAM
// row-activate storm; rows block-exclusive -> no race with the zeroing.
__global__ __launch_bounds__(BLK) void fill_patch(
    const float* __restrict__ vals,   // [MM,2]
    const int* __restrict__ coo,      // [2,MM]
    const int* __restrict__ cnt,      // [NN]
    const int* __restrict__ bins,     // [NN,MAXB]
    float* __restrict__ out)          // [DD*DD]
{
    const int bid = blockIdx.x;        // 0..2*NN-1
    const int i   = bid >> 1;
    const int mj  = bid & 1;
    const int tid = threadIdx.x;

    float* __restrict__ rowp = out + (size_t)(2 * i + mj) * DD;

    // Phase 1: stream the 48KB row of zeros (coalesced float4).
    const float4 z = make_float4(0.f, 0.f, 0.f, 0.f);
    for (int j = tid; j < DD / 4; j += BLK) ((float4*)rowp)[j] = z;

    // gfx950 __syncthreads emits s_waitcnt vmcnt(0) before s_barrier:
    // every store above has reached L2 (coherence point) before any patch.
    __syncthreads();

    // Phase 2: patch entries — L2-hit atomics, no DRAM activates.
    int n = cnt[i];
    n = n < 0 ? 0 : (n > MAXB ? MAXB : n);
    for (int e = tid; e < n; e += BLK) {
        const int m = bins[i * MAXB + e];
        const int c = coo[MM + m] * 2 + mj;
        unsafeAtomicAdd(rowp + c, vals[2 * m + mj]);
    }
}

__global__ __launch_bounds__(BLK) void scatter_add(   // fallback path
    const float* __restrict__ vals, const int* __restrict__ coo,
    float* __restrict__ out)
{
    const int t = blockIdx.x * BLK + threadIdx.x;
    if (t >= MM) return;
    const int r2 = coo[t] * 2;
    const int c2 = coo[MM + t] * 2;
    const float2 v = *(const float2*)(vals + 2 * t);
    const long long f0 = (long long)r2 * DD + c2;
    unsafeAtomicAdd(out + f0, v.x);
    unsafeAtomicAdd(out + f0 + DD + 1, v.y);
}

extern "C" void kernel_launch(void* const* d_in, const int* in_sizes, int n_in,
                              void* d_out, int out_size, void* d_ws, size_t ws_size,
                              hipStream_t stream) {
    const float* CK   = (const float*)d_in[0];
    const float* Win  = (const float*)d_in[1];
    const float* bin  = (const float*)d_in[2];
    const float* Whid = (const float*)d_in[3];
    const float* bhid = (const float*)d_in[4];
    const float* Wout = (const float*)d_in[5];
    const float* bout = (const float*)d_in[6];
    const int* coo    = (const int*)d_in[7];
    float* out        = (float*)d_out;
    float* vals       = (float*)d_ws;

    if (ws_size >= (size_t)WS_NEEDED) {
        int* cnt  = (int*)((char*)d_ws + VALS_B);
        int* bins = (int*)((char*)d_ws + VALS_B + CNT_B);
        zero_cnt<<<(NN + BLK - 1) / BLK, BLK, 0, stream>>>(cnt);
        mlp_bin<<<MLPGRID, BLK, 0, stream>>>(
            CK, Win, bin, Whid, bhid, Wout, bout, coo, vals, cnt, bins, 1);
        fill_patch<<<2 * NN, BLK, 0, stream>>>(vals, coo, cnt, bins, out);
    } else {
        // Fallback (small ws): R9 structure — memset + mlp + atomic scatter.
        hipMemsetAsync(out, 0, OUTBYTES, stream);
        mlp_bin<<<MLPGRID, BLK, 0, stream>>>(
            CK, Win, bin, Whid, bhid, Wout, bout, coo, vals, nullptr, nullptr, 0);
        scatter_add<<<SCGRID, BLK, 0, stream>>>(vals, coo, out);
    }
}

// Round 18
// 660.831 us; speedup vs baseline: 1.0396x; 1.0066x over previous
//
#include <hip/hip_runtime.h>
#include <stdint.h>

#define NN    6000
#define KNNC  10
#define MM    (NN * 2 * (KNNC + 1))   // 132000
#define DD    (2 * NN)                // 12000
#define LCH   3                       // hidden layers (LC-1)
#define BLK   256

#define RB     128                     // rows per MLP block
#define RPL    2                       // rows per lane
#define MLPGRID ((MM + RB - 1) / RB)   // 1032
#define SCGRID  ((MM + BLK - 1) / BLK) // 516 (fallback)
#define OUTBYTES ((size_t)DD * DD * 4) // 576,000,000

#define MAXB     128                   // bucket capacity (R15/R17 passing => no overflow)
#define PROWS    4                     // rows per patch block (1 wave per row)
#define VALS_B   (MM * 2 * 4)          // 1,056,000
#define CNT_B    (NN * 4)              // 24,000
#define BINS_B   (NN * MAXB * 4)       // 3,072,000
#define WS_NEEDED (VALS_B + CNT_B + BINS_B)   // 4,152,000

// Round-18. Model closed by R9/R11 (memset|fill + M9 = 149-150 twice),
// R2/R16 (scatter = 125 direct; CAS==native => not the atomic protocol but
// a scattered-RMW throughput cap ~2/ns), R15/R17 (row-owner fills = 216/233
// -> per-block drain bubbles, never build rows in-kernel). Plateau = 375
// poison + 94 memset + ~60 mlp + 125 scatter = ~650. The untested escape:
// ZERO-ATOMIC patch. Bins (proven) group couplings by destination row;
// duplicates within a row are rare -> one wave per row loads <=45 entries
// to LDS, O(n^2) scans for duplicate columns (n~22), owners issue PLAIN 4B
// stores into the memset'd rows (proven store path, no atomic unit). If
// scattered plain stores bypass the cap: patch ~15-40us, -100 vs scatter.
__global__ void zero_cnt(int* __restrict__ cnt) {
    const int i = blockIdx.x * BLK + threadIdx.x;
    if (i < NN) cnt[i] = 0;
}

__global__ __launch_bounds__(BLK, 4) void mlp_bin(
    const float* __restrict__ CK,    // [MM,3]
    const float* __restrict__ Win,   // [3,64]
    const float* __restrict__ bin,   // [64]
    const float* __restrict__ Whid,  // [3,64,64]
    const float* __restrict__ bhid,  // [3,64]
    const float* __restrict__ Wout,  // [64,4]
    const float* __restrict__ bout,  // [4]
    const int* __restrict__ coo,     // [2,MM]
    float* __restrict__ vals,        // [MM,2]
    int* __restrict__ cnt,           // [NN] (pre-zeroed) or null
    int* __restrict__ bins,          // [NN,MAXB] or null
    const int do_bins)
{
    __shared__ float sH[64 * RB];    // activations [k][row], row=lane*2+r, 32 KiB

    const int tid  = threadIdx.x;
    const int wave = tid >> 6;
    const int lane = tid & 63;
    // Wave-uniform channel offset in an SGPR -> weight loads scalarize.
    const int jo = __builtin_amdgcn_readfirstlane((tid >> 6) << 4);

    const int rbase = blockIdx.x * RB;
    const int mb0   = rbase + lane * 2;        // lane's first row (even)
    const int mb    = mb0 < MM ? mb0 : MM - 2; // clamp loads, guard stores

    // Lane's 2 rows of inputs: 6 consecutive floats -> 3 float2.
    const float2 ca = *(const float2*)(CK + mb * 3);      // x0r0 x1r0
    const float2 cb = *(const float2*)(CK + mb * 3 + 2);  // x2r0 x0r1
    const float2 cc = *(const float2*)(CK + mb * 3 + 4);  // x1r1 x2r1
    const float x0[RPL] = {ca.x, cb.y};
    const float x1[RPL] = {ca.y, cc.x};
    const float x2[RPL] = {cb.x, cc.y};

    // Input layer: this wave's 16 channels for its 2 packed rows.
#pragma unroll
    for (int jj = 0; jj < 16; jj++) {
        const int j = jo + jj;
        const float w0 = Win[j], w1 = Win[64 + j], w2 = Win[128 + j];  // s_load
        const float bj = bin[j];
        float2 hv;
        hv.x = fmaxf(fmaf(x2[0], w2, fmaf(x1[0], w1, fmaf(x0[0], w0, bj))), 0.f);
        hv.y = fmaxf(fmaf(x2[1], w2, fmaf(x1[1], w1, fmaf(x0[1], w0, bj))), 0.f);
        *(float2*)(sH + j * RB + lane * 2) = hv;
    }
    __syncthreads();

    // Hidden layers, barrier-lockstep (all waves on the same 16KB W -> K$-hot).
#pragma unroll 1
    for (int l = 0; l < LCH; l++) {
        const float* __restrict__ Wl = Whid + (l << 12) + jo;  // uniform SGPR base
        const float* __restrict__ bh = bhid + (l << 6) + jo;

        float g[RPL][16];
#pragma unroll
        for (int jj = 0; jj < 16; jj++) {
            const float bj = bh[jj];           // s_load
            g[0][jj] = bj;
            g[1][jj] = bj;
        }

#pragma unroll 4
        for (int k = 0; k < 64; k++) {
            // This wave's 16-channel weight slice: 64B uniform -> s_load.
            const float4 wa = *(const float4*)(Wl + (k << 6));
            const float4 wb = *(const float4*)(Wl + (k << 6) + 4);
            const float4 wc = *(const float4*)(Wl + (k << 6) + 8);
            const float4 wd = *(const float4*)(Wl + (k << 6) + 12);
            const float2 hv = *(const float2*)(sH + k * RB + lane * 2);
            const float hk[RPL] = {hv.x, hv.y};
#pragma unroll
            for (int r = 0; r < RPL; r++) {
                g[r][0]  = fmaf(wa.x, hk[r], g[r][0]);
                g[r][1]  = fmaf(wa.y, hk[r], g[r][1]);
                g[r][2]  = fmaf(wa.z, hk[r], g[r][2]);
                g[r][3]  = fmaf(wa.w, hk[r], g[r][3]);
                g[r][4]  = fmaf(wb.x, hk[r], g[r][4]);
                g[r][5]  = fmaf(wb.y, hk[r], g[r][5]);
                g[r][6]  = fmaf(wb.z, hk[r], g[r][6]);
                g[r][7]  = fmaf(wb.w, hk[r], g[r][7]);
                g[r][8]  = fmaf(wc.x, hk[r], g[r][8]);
                g[r][9]  = fmaf(wc.y, hk[r], g[r][9]);
                g[r][10] = fmaf(wc.z, hk[r], g[r][10]);
                g[r][11] = fmaf(wc.w, hk[r], g[r][11]);
                g[r][12] = fmaf(wd.x, hk[r], g[r][12]);
                g[r][13] = fmaf(wd.y, hk[r], g[r][13]);
                g[r][14] = fmaf(wd.z, hk[r], g[r][14]);
                g[r][15] = fmaf(wd.w, hk[r], g[r][15]);
            }
        }
        __syncthreads();   // all reads of sH for layer l complete

        // relu + writeback: 16 b64 (2 packed rows per channel).
#pragma unroll
        for (int jj = 0; jj < 16; jj++) {
            float2 hv;
            hv.x = fmaxf(g[0][jj], 0.f);
            hv.y = fmaxf(g[1][jj], 0.f);
            *(float2*)(sH + (jo + jj) * RB + lane * 2) = hv;
        }
        __syncthreads();   // h ready for next layer / output
    }

    // Output layer collapsed over mi: v[:,mj] = C[:,mj] + C[:,mj+2].
    float v0[RPL], v1[RPL];
    const float b02 = bout[0] + bout[2], b13 = bout[1] + bout[3];
#pragma unroll
    for (int r = 0; r < RPL; r++) { v0[r] = b02; v1[r] = b13; }
#pragma unroll 8
    for (int k = 0; k < 64; k++) {
        const float4 wo = ((const float4*)Wout)[k];     // s_load
        const float wxz = wo.x + wo.z, wyw = wo.y + wo.w;
        const float2 hv = *(const float2*)(sH + k * RB + lane * 2);
        v0[0] = fmaf(hv.x, wxz, v0[0]);  v1[0] = fmaf(hv.x, wyw, v1[0]);
        v0[1] = fmaf(hv.y, wxz, v0[1]);  v1[1] = fmaf(hv.y, wyw, v1[1]);
    }
    if (wave == 0 && mb0 < MM) {
        *(float4*)(vals + 2 * mb0) = make_float4(v0[0], v1[0], v0[1], v1[1]);
        if (do_bins) {
            // Bin both rows by destination row index i = coo0[m].
#pragma unroll
            for (int r = 0; r < RPL; r++) {
                const int m = mb0 + r;
                const int i = coo[m];
                const int pos = atomicAdd(&cnt[i], 1);
                if (pos < MAXB) bins[i * MAXB + pos] = m;
            }
        }
    }
}

// Zero-atomic patch: wave w of block b owns row i = b*PROWS + w. Load its
// n<=MAXB entries into per-wave LDS, O(n^2) duplicate-column scan (n~22),
// owner lanes plain-store the deduped sums into the memset'd output rows
// 2i (v0 @ col 2j) and 2i+1 (v1 @ col 2j+1). No atomics anywhere.
__global__ __launch_bounds__(BLK) void patch_rows(
    const float* __restrict__ vals,   // [MM,2]
    const int* __restrict__ coo,      // [2,MM]
    const int* __restrict__ cnt,      // [NN]
    const int* __restrict__ bins,     // [NN,MAXB]
    float* __restrict__ out)          // [DD*DD], pre-zeroed by memset
{
    __shared__ int   cols[PROWS][MAXB];
    __shared__ float sv0[PROWS][MAXB];
    __shared__ float sv1[PROWS][MAXB];

    const int tid  = threadIdx.x;
    const int w    = tid >> 6;
    const int lane = tid & 63;
    const int i    = blockIdx.x * PROWS + w;
    if (i >= NN) return;

    int n = cnt[i];
    n = n < 0 ? 0 : (n > MAXB ? MAXB : n);

    // Load phase: entries e = lane, lane+64.
    for (int e = lane; e < n; e += 64) {
        const int m = bins[i * MAXB + e];
        cols[w][e] = coo[MM + m];
        const float2 v = *(const float2*)(vals + 2 * m);
        sv0[w][e] = v.x;
        sv1[w][e] = v.y;
    }
    __syncthreads();   // belt-and-braces (per-wave arrays; barrier is cheap)

    // Scan + store phase: owner = first entry with this column.
    for (int e = lane; e < n; e += 64) {
        const int c = cols[w][e];
        int first = -1;
        float t0 = 0.f, t1 = 0.f;
        for (int j = 0; j < n; j++) {           // n~22; LDS broadcast reads
            if (cols[w][j] == c) {
                if (first < 0) first = j;
                t0 += sv0[w][j];
                t1 += sv1[w][j];
            }
        }
        if (first == e) {
            // plain 4B stores into L2/DRAM (store path, no atomic unit)
            out[(size_t)(2 * i) * DD + 2 * c]           = t0;
            out[(size_t)(2 * i + 1) * DD + 2 * c + 1]   = t1;
        }
    }
}

__global__ __launch_bounds__(BLK) void scatter_add(   // fallback path
    const float* __restrict__ vals, const int* __restrict__ coo,
    float* __restrict__ out)
{
    const int t = blockIdx.x * BLK + threadIdx.x;
    if (t >= MM) return;
    const int r2 = coo[t] * 2;
    const int c2 = coo[MM + t] * 2;
    const float2 v = *(const float2*)(vals + 2 * t);
    const long long f0 = (long long)r2 * DD + c2;
    unsafeAtomicAdd(out + f0, v.x);
    unsafeAtomicAdd(out + f0 + DD + 1, v.y);
}

extern "C" void kernel_launch(void* const* d_in, const int* in_sizes, int n_in,
                              void* d_out, int out_size, void* d_ws, size_t ws_size,
                              hipStream_t stream) {
    const float* CK   = (const float*)d_in[0];
    const float* Win  = (const float*)d_in[1];
    const float* bin  = (const float*)d_in[2];
    const float* Whid = (const float*)d_in[3];
    const float* bhid = (const float*)d_in[4];
    const float* Wout = (const float*)d_in[5];
    const float* bout = (const float*)d_in[6];
    const int* coo    = (const int*)d_in[7];
    float* out        = (float*)d_out;
    float* vals       = (float*)d_ws;

    if (ws_size >= (size_t)WS_NEEDED) {
        int* cnt  = (int*)((char*)d_ws + VALS_B);
        int* bins = (int*)((char*)d_ws + VALS_B + CNT_B);
        zero_cnt<<<(NN + BLK - 1) / BLK, BLK, 0, stream>>>(cnt);
        mlp_bin<<<MLPGRID, BLK, 0, stream>>>(
            CK, Win, bin, Whid, bhid, Wout, bout, coo, vals, cnt, bins, 1);
        hipMemsetAsync(out, 0, OUTBYTES, stream);   // rocclr fill, 94us proven
        patch_rows<<<(NN + PROWS - 1) / PROWS, BLK, 0, stream>>>(
            vals, coo, cnt, bins, out);
    } else {
        // Fallback (small ws): R9 structure — memset + mlp + atomic scatter.
        hipMemsetAsync(out, 0, OUTBYTES, stream);
        mlp_bin<<<MLPGRID, BLK, 0, stream>>>(
            CK, Win, bin, Whid, bhid, Wout, bout, coo, vals, nullptr, nullptr, 0);
        scatter_add<<<SCGRID, BLK, 0, stream>>>(vals, coo, out);
    }
}

// Round 19
// 657.523 us; speedup vs baseline: 1.0448x; 1.0050x over previous
//
#include <hip/hip_runtime.h>
#include <stdint.h>

#define NN    6000
#define KNNC  10
#define MM    (NN * 2 * (KNNC + 1))   // 132000
#define DD    (2 * NN)                // 12000
#define LCH   3                       // hidden layers (LC-1)
#define BLK   256

#define RB     128                     // rows per MLP block
#define RPL    2                       // rows per lane
#define MLPGRID ((MM + RB - 1) / RB)   // 1032
#define SCGRID  ((MM + BLK - 1) / BLK) // 516

#define NCHUNK  4
#define ICHUNK  (NN / NCHUNK)          // 1500 destination indices per chunk
#define CHUNKB  ((size_t)ICHUNK * 2 * DD * 4)   // 144,000,000 bytes

// Round-19: residency is the last un-isolated variable. R2/R16/R18 proved
// the ~125us scatter cost is mechanism-invariant (CAS atomic == native
// atomic == plain 4B store == L2-patch): ~264k scattered sub-line writes
// into a 576MB mostly-DRAM-resident buffer -> line-fill + row-activate
// each. Fix: chunk the output into 4 x 144MB slices (<< 256MB Infinity
// Cache). Per slice: hipMemsetAsync (rocclr path, full BW) then IMMEDIATELY
// patch_chunk - grid-stride over all couplings, filter i in [i0,i1), two
// unsafeAtomicAdds. The slice's lines are still L3-resident (memory-side
// cache absorbs memset writes) -> scattered atomics hit L3, no DRAM
// activates. coo/vals (2.1MB) stay L2-hot across passes. Same total memset
// bytes. Binning machinery dropped (not needed). Falsifier: >=640 means
// residency doesn't matter -> scatter-path cap is structural and
// 375+94+55+125~=650 is the floor.

__global__ __launch_bounds__(BLK, 4) void mlp(
    const float* __restrict__ CK,    // [MM,3]
    const float* __restrict__ Win,   // [3,64]
    const float* __restrict__ bin,   // [64]
    const float* __restrict__ Whid,  // [3,64,64]
    const float* __restrict__ bhid,  // [3,64]
    const float* __restrict__ Wout,  // [64,4]
    const float* __restrict__ bout,  // [4]
    float* __restrict__ vals)        // [MM,2]
{
    __shared__ float sH[64 * RB];    // activations [k][row], row=lane*2+r, 32 KiB

    const int tid  = threadIdx.x;
    const int wave = tid >> 6;
    const int lane = tid & 63;
    // Wave-uniform channel offset in an SGPR -> weight loads scalarize.
    const int jo = __builtin_amdgcn_readfirstlane((tid >> 6) << 4);

    const int rbase = blockIdx.x * RB;
    const int mb0   = rbase + lane * 2;        // lane's first row (even)
    const int mb    = mb0 < MM ? mb0 : MM - 2; // clamp loads, guard stores

    // Lane's 2 rows of inputs: 6 consecutive floats -> 3 float2.
    const float2 ca = *(const float2*)(CK + mb * 3);      // x0r0 x1r0
    const float2 cb = *(const float2*)(CK + mb * 3 + 2);  // x2r0 x0r1
    const float2 cc = *(const float2*)(CK + mb * 3 + 4);  // x1r1 x2r1
    const float x0[RPL] = {ca.x, cb.y};
    const float x1[RPL] = {ca.y, cc.x};
    const float x2[RPL] = {cb.x, cc.y};

    // Input layer: this wave's 16 channels for its 2 packed rows.
#pragma unroll
    for (int jj = 0; jj < 16; jj++) {
        const int j = jo + jj;
        const float w0 = Win[j], w1 = Win[64 + j], w2 = Win[128 + j];  // s_load
        const float bj = bin[j];
        float2 hv;
        hv.x = fmaxf(fmaf(x2[0], w2, fmaf(x1[0], w1, fmaf(x0[0], w0, bj))), 0.f);
        hv.y = fmaxf(fmaf(x2[1], w2, fmaf(x1[1], w1, fmaf(x0[1], w0, bj))), 0.f);
        *(float2*)(sH + j * RB + lane * 2) = hv;
    }
    __syncthreads();

    // Hidden layers, barrier-lockstep (all waves on the same 16KB W -> K$-hot).
#pragma unroll 1
    for (int l = 0; l < LCH; l++) {
        const float* __restrict__ Wl = Whid + (l << 12) + jo;  // uniform SGPR base
        const float* __restrict__ bh = bhid + (l << 6) + jo;

        float g[RPL][16];
#pragma unroll
        for (int jj = 0; jj < 16; jj++) {
            const float bj = bh[jj];           // s_load
            g[0][jj] = bj;
            g[1][jj] = bj;
        }

#pragma unroll 4
        for (int k = 0; k < 64; k++) {
            // This wave's 16-channel weight slice: 64B uniform -> s_load.
            const float4 wa = *(const float4*)(Wl + (k << 6));
            const float4 wb = *(const float4*)(Wl + (k << 6) + 4);
            const float4 wc = *(const float4*)(Wl + (k << 6) + 8);
            const float4 wd = *(const float4*)(Wl + (k << 6) + 12);
            const float2 hv = *(const float2*)(sH + k * RB + lane * 2);
            const float hk[RPL] = {hv.x, hv.y};
#pragma unroll
            for (int r = 0; r < RPL; r++) {
                g[r][0]  = fmaf(wa.x, hk[r], g[r][0]);
                g[r][1]  = fmaf(wa.y, hk[r], g[r][1]);
                g[r][2]  = fmaf(wa.z, hk[r], g[r][2]);
                g[r][3]  = fmaf(wa.w, hk[r], g[r][3]);
                g[r][4]  = fmaf(wb.x, hk[r], g[r][4]);
                g[r][5]  = fmaf(wb.y, hk[r], g[r][5]);
                g[r][6]  = fmaf(wb.z, hk[r], g[r][6]);
                g[r][7]  = fmaf(wb.w, hk[r], g[r][7]);
                g[r][8]  = fmaf(wc.x, hk[r], g[r][8]);
                g[r][9]  = fmaf(wc.y, hk[r], g[r][9]);
                g[r][10] = fmaf(wc.z, hk[r], g[r][10]);
                g[r][11] = fmaf(wc.w, hk[r], g[r][11]);
                g[r][12] = fmaf(wd.x, hk[r], g[r][12]);
                g[r][13] = fmaf(wd.y, hk[r], g[r][13]);
                g[r][14] = fmaf(wd.z, hk[r], g[r][14]);
                g[r][15] = fmaf(wd.w, hk[r], g[r][15]);
            }
        }
        __syncthreads();   // all reads of sH for layer l complete

        // relu + writeback: 16 b64 (2 packed rows per channel).
#pragma unroll
        for (int jj = 0; jj < 16; jj++) {
            float2 hv;
            hv.x = fmaxf(g[0][jj], 0.f);
            hv.y = fmaxf(g[1][jj], 0.f);
            *(float2*)(sH + (jo + jj) * RB + lane * 2) = hv;
        }
        __syncthreads();   // h ready for next layer / output
    }

    // Output layer collapsed over mi: v[:,mj] = C[:,mj] + C[:,mj+2].
    float v0[RPL], v1[RPL];
    const float b02 = bout[0] + bout[2], b13 = bout[1] + bout[3];
#pragma unroll
    for (int r = 0; r < RPL; r++) { v0[r] = b02; v1[r] = b13; }
#pragma unroll 8
    for (int k = 0; k < 64; k++) {
        const float4 wo = ((const float4*)Wout)[k];     // s_load
        const float wxz = wo.x + wo.z, wyw = wo.y + wo.w;
        const float2 hv = *(const float2*)(sH + k * RB + lane * 2);
        v0[0] = fmaf(hv.x, wxz, v0[0]);  v1[0] = fmaf(hv.x, wyw, v1[0]);
        v0[1] = fmaf(hv.y, wxz, v0[1]);  v1[1] = fmaf(hv.y, wyw, v1[1]);
    }
    if (wave == 0 && mb0 < MM) {
        // rows mb0, mb0+1 -> one 16B store.
        *(float4*)(vals + 2 * mb0) = make_float4(v0[0], v1[0], v0[1], v1[1]);
    }
}

// Patch pass for destination indices i in [i0, i1): runs immediately after
// that slice's memset, so the slice is L3-resident -> scattered atomics are
// L3 hits (no DRAM line-fill / row-activate). coo & vals are L2-hot.
__global__ __launch_bounds__(BLK) void patch_chunk(
    const float* __restrict__ vals,   // [MM,2]
    const int* __restrict__ coo,      // [2,MM]
    float* __restrict__ out,          // [DD*DD]
    const int i0, const int i1)
{
    const int t = blockIdx.x * BLK + threadIdx.x;
    if (t >= MM) return;
    const int i = coo[t];
    if (i < i0 || i >= i1) return;
    const int c2 = coo[MM + t] * 2;
    const float2 v = *(const float2*)(vals + 2 * t);
    const long long f0 = (long long)(i * 2) * DD + c2;
    unsafeAtomicAdd(out + f0, v.x);            // (2i, 2j)   — L3-hit
    unsafeAtomicAdd(out + f0 + DD + 1, v.y);   // (2i+1, 2j+1)
}

extern "C" void kernel_launch(void* const* d_in, const int* in_sizes, int n_in,
                              void* d_out, int out_size, void* d_ws, size_t ws_size,
                              hipStream_t stream) {
    const float* CK   = (const float*)d_in[0];
    const float* Win  = (const float*)d_in[1];
    const float* bin  = (const float*)d_in[2];
    const float* Whid = (const float*)d_in[3];
    const float* bhid = (const float*)d_in[4];
    const float* Wout = (const float*)d_in[5];
    const float* bout = (const float*)d_in[6];
    const int* coo    = (const int*)d_in[7];
    float* out        = (float*)d_out;
    float* vals       = (float*)d_ws;

    mlp<<<MLPGRID, BLK, 0, stream>>>(CK, Win, bin, Whid, bhid, Wout, bout, vals);

    // Chunked zero + L3-hot patch: slice c covers i in [c*1500,(c+1)*1500)
    // = output rows [c*3000, (c+1)*3000) = 144MB contiguous (< 256MB L3).
    for (int c = 0; c < NCHUNK; c++) {
        float* slice = out + (size_t)c * ICHUNK * 2 * DD;
        hipMemsetAsync(slice, 0, CHUNKB, stream);
        patch_chunk<<<SCGRID, BLK, 0, stream>>>(
            vals, coo, out, c * ICHUNK, (c + 1) * ICHUNK);
    }
}

// Round 21
// 652.053 us; speedup vs baseline: 1.0536x; 1.0084x over previous
//
#include <hip/hip_runtime.h>
#include <stdint.h>

#define NN    6000
#define KNNC  10
#define MM    (NN * 2 * (KNNC + 1))   // 132000
#define DD    (2 * NN)                // 12000
#define LCH   3                       // hidden layers (LC-1)
#define BLK   256

#define RB     128                     // rows per MLP block
#define RPL    2                       // rows per lane
#define MLPGRID ((MM + RB - 1) / RB)   // 1032
#define SCGRID  ((MM + BLK - 1) / BLK) // 516 (fallback)
#define OUTBYTES ((size_t)DD * DD * 4) // 576,000,000

#define MAXB     128                   // bucket capacity (R15/17/18 passed => no overflow)
#define NF4      (DD / 4)              // 3000 float4 slots per row
#define NBW      96                    // bitmap words (ceil(3000/32)=94, padded)
#define VALS_B   (MM * 2 * 4)          // 1,056,000
#define CNT_B    (NN * 4)              // 24,000
#define BINS_B   (NN * MAXB * 4)       // 3,072,000
#define WS_NEEDED (VALS_B + CNT_B + BINS_B)   // 4,152,000

// Round-21 = Round-20 resubmitted (R20 died at container acquisition like
// R13/R14: no timing dict, no pytest -> infra; R15's resubmission of the
// same machinery ran and passed). Theory unchanged: merge the patches INTO
// the zero stream. fill_merge: block i owns rows 2i/2i+1; stage its n<=128
// entries + a 3000-bit f4-slot bitmap in ~2.4KB LDS (both rows share slot
// c>>1); each thread streams ~12 float4 slots x 2 rows: 1 LDS bit-test
// each, 99.3% pure store, flagged slots (~22/row) scan n statically.
// No atomics, no memset, no LDS row buffer; every output element written
// exactly once. Replaces the 219us memset+scatter pair with ~105-140us of
// streaming. Falsifier: >=640 => row-owner stores capped intrinsically;
// ~650 = demonstrated floor.

__global__ void zero_cnt(int* __restrict__ cnt) {
    const int i = blockIdx.x * BLK + threadIdx.x;
    if (i < NN) cnt[i] = 0;
}

__global__ __launch_bounds__(BLK, 4) void mlp_bin(
    const float* __restrict__ CK,    // [MM,3]
    const float* __restrict__ Win,   // [3,64]
    const float* __restrict__ bin,   // [64]
    const float* __restrict__ Whid,  // [3,64,64]
    const float* __restrict__ bhid,  // [3,64]
    const float* __restrict__ Wout,  // [64,4]
    const float* __restrict__ bout,  // [4]
    const int* __restrict__ coo,     // [2,MM]
    float* __restrict__ vals,        // [MM,2]
    int* __restrict__ cnt,           // [NN] (pre-zeroed) or null
    int* __restrict__ bins,          // [NN,MAXB] or null
    const int do_bins)
{
    __shared__ float sH[64 * RB];    // activations [k][row], row=lane*2+r, 32 KiB

    const int tid  = threadIdx.x;
    const int wave = tid >> 6;
    const int lane = tid & 63;
    const int jo = __builtin_amdgcn_readfirstlane((tid >> 6) << 4);

    const int rbase = blockIdx.x * RB;
    const int mb0   = rbase + lane * 2;        // lane's first row (even)
    const int mb    = mb0 < MM ? mb0 : MM - 2; // clamp loads, guard stores

    const float2 ca = *(const float2*)(CK + mb * 3);      // x0r0 x1r0
    const float2 cb = *(const float2*)(CK + mb * 3 + 2);  // x2r0 x0r1
    const float2 cc = *(const float2*)(CK + mb * 3 + 4);  // x1r1 x2r1
    const float x0[RPL] = {ca.x, cb.y};
    const float x1[RPL] = {ca.y, cc.x};
    const float x2[RPL] = {cb.x, cc.y};

    // Input layer: this wave's 16 channels for its 2 packed rows.
#pragma unroll
    for (int jj = 0; jj < 16; jj++) {
        const int j = jo + jj;
        const float w0 = Win[j], w1 = Win[64 + j], w2 = Win[128 + j];  // s_load
        const float bj = bin[j];
        float2 hv;
        hv.x = fmaxf(fmaf(x2[0], w2, fmaf(x1[0], w1, fmaf(x0[0], w0, bj))), 0.f);
        hv.y = fmaxf(fmaf(x2[1], w2, fmaf(x1[1], w1, fmaf(x0[1], w0, bj))), 0.f);
        *(float2*)(sH + j * RB + lane * 2) = hv;
    }
    __syncthreads();

    // Hidden layers, barrier-lockstep (all waves on the same 16KB W -> K$-hot).
#pragma unroll 1
    for (int l = 0; l < LCH; l++) {
        const float* __restrict__ Wl = Whid + (l << 12) + jo;
        const float* __restrict__ bh = bhid + (l << 6) + jo;

        float g[RPL][16];
#pragma unroll
        for (int jj = 0; jj < 16; jj++) {
            const float bj = bh[jj];
            g[0][jj] = bj;
            g[1][jj] = bj;
        }

#pragma unroll 4
        for (int k = 0; k < 64; k++) {
            const float4 wa = *(const float4*)(Wl + (k << 6));
            const float4 wb = *(const float4*)(Wl + (k << 6) + 4);
            const float4 wc = *(const float4*)(Wl + (k << 6) + 8);
            const float4 wd = *(const float4*)(Wl + (k << 6) + 12);
            const float2 hv = *(const float2*)(sH + k * RB + lane * 2);
            const float hk[RPL] = {hv.x, hv.y};
#pragma unroll
            for (int r = 0; r < RPL; r++) {
                g[r][0]  = fmaf(wa.x, hk[r], g[r][0]);
                g[r][1]  = fmaf(wa.y, hk[r], g[r][1]);
                g[r][2]  = fmaf(wa.z, hk[r], g[r][2]);
                g[r][3]  = fmaf(wa.w, hk[r], g[r][3]);
                g[r][4]  = fmaf(wb.x, hk[r], g[r][4]);
                g[r][5]  = fmaf(wb.y, hk[r], g[r][5]);
                g[r][6]  = fmaf(wb.z, hk[r], g[r][6]);
                g[r][7]  = fmaf(wb.w, hk[r], g[r][7]);
                g[r][8]  = fmaf(wc.x, hk[r], g[r][8]);
                g[r][9]  = fmaf(wc.y, hk[r], g[r][9]);
                g[r][10] = fmaf(wc.z, hk[r], g[r][10]);
                g[r][11] = fmaf(wc.w, hk[r], g[r][11]);
                g[r][12] = fmaf(wd.x, hk[r], g[r][12]);
                g[r][13] = fmaf(wd.y, hk[r], g[r][13]);
                g[r][14] = fmaf(wd.z, hk[r], g[r][14]);
                g[r][15] = fmaf(wd.w, hk[r], g[r][15]);
            }
        }
        __syncthreads();

#pragma unroll
        for (int jj = 0; jj < 16; jj++) {
            float2 hv;
            hv.x = fmaxf(g[0][jj], 0.f);
            hv.y = fmaxf(g[1][jj], 0.f);
            *(float2*)(sH + (jo + jj) * RB + lane * 2) = hv;
        }
        __syncthreads();
    }

    // Output layer collapsed over mi: v[:,mj] = C[:,mj] + C[:,mj+2].
    float v0[RPL], v1[RPL];
    const float b02 = bout[0] + bout[2], b13 = bout[1] + bout[3];
#pragma unroll
    for (int r = 0; r < RPL; r++) { v0[r] = b02; v1[r] = b13; }
#pragma unroll 8
    for (int k = 0; k < 64; k++) {
        const float4 wo = ((const float4*)Wout)[k];
        const float wxz = wo.x + wo.z, wyw = wo.y + wo.w;
        const float2 hv = *(const float2*)(sH + k * RB + lane * 2);
        v0[0] = fmaf(hv.x, wxz, v0[0]);  v1[0] = fmaf(hv.x, wyw, v1[0]);
        v0[1] = fmaf(hv.y, wxz, v0[1]);  v1[1] = fmaf(hv.y, wyw, v1[1]);
    }
    if (wave == 0 && mb0 < MM) {
        *(float4*)(vals + 2 * mb0) = make_float4(v0[0], v1[0], v0[1], v1[1]);
        if (do_bins) {
#pragma unroll
            for (int r = 0; r < RPL; r++) {
                const int m = mb0 + r;
                const int i = coo[m];
                const int pos = atomicAdd(&cnt[i], 1);
                if (pos < MAXB) bins[i * MAXB + pos] = m;
            }
        }
    }
}

// Merged fill: block i writes output rows 2i and 2i+1 as one zero stream
// with its couplings merged in-register. Slot bitmap: column c patches f4
// slot c>>1 in BOTH rows (row 2i elem (c&1)*2, row 2i+1 elem (c&1)*2+1).
// Fast path (99.3% of slots): bit clear -> pure float4 stores.
__global__ __launch_bounds__(BLK) void fill_merge(
    const float* __restrict__ vals,   // [MM,2]
    const int* __restrict__ coo,      // [2,MM]
    const int* __restrict__ cnt,      // [NN]
    const int* __restrict__ bins,     // [NN,MAXB]
    float* __restrict__ out)          // [DD*DD]
{
    __shared__ unsigned bmap[NBW];    // 3000-bit f4-slot bitmap
    __shared__ int   scol[MAXB];
    __shared__ float sv0[MAXB];
    __shared__ float sv1[MAXB];

    const int i   = blockIdx.x;       // 0..NN-1
    const int tid = threadIdx.x;

    int n = cnt[i];
    n = n < 0 ? 0 : (n > MAXB ? MAXB : n);

    if (tid < NBW) bmap[tid] = 0u;
    __syncthreads();

    if (tid < n) {
        const int m = bins[i * MAXB + tid];
        const int c = coo[MM + m];
        scol[tid] = c;
        const float2 v = *(const float2*)(vals + 2 * m);
        sv0[tid] = v.x;
        sv1[tid] = v.y;
        const int s = c >> 1;
        atomicOr(&bmap[s >> 5], 1u << (s & 31));
    }
    __syncthreads();

    float4* __restrict__ r0 = (float4*)(out + (size_t)(2 * i) * DD);
    float4* __restrict__ r1 = (float4*)(out + (size_t)(2 * i + 1) * DD);

    for (int f = tid; f < NF4; f += BLK) {
        float4 a = make_float4(0.f, 0.f, 0.f, 0.f);   // row 2i
        float4 b = make_float4(0.f, 0.f, 0.f, 0.f);   // row 2i+1
        if (bmap[f >> 5] & (1u << (f & 31))) {        // rare (~22/3000)
            for (int e = 0; e < n; e++) {             // LDS broadcast reads
                const int c = scol[e];
                if ((c >> 1) == f) {
                    if ((c & 1) == 0) { a.x += sv0[e]; b.y += sv1[e]; }
                    else              { a.z += sv0[e]; b.w += sv1[e]; }
                }
            }
        }
        r0[f] = a;
        r1[f] = b;
    }
}

__global__ __launch_bounds__(BLK) void scatter_add(   // fallback path
    const float* __restrict__ vals, const int* __restrict__ coo,
    float* __restrict__ out)
{
    const int t = blockIdx.x * BLK + threadIdx.x;
    if (t >= MM) return;
    const int r2 = coo[t] * 2;
    const int c2 = coo[MM + t] * 2;
    const float2 v = *(const float2*)(vals + 2 * t);
    const long long f0 = (long long)r2 * DD + c2;
    unsafeAtomicAdd(out + f0, v.x);
    unsafeAtomicAdd(out + f0 + DD + 1, v.y);
}

extern "C" void kernel_launch(void* const* d_in, const int* in_sizes, int n_in,
                              void* d_out, int out_size, void* d_ws, size_t ws_size,
                              hipStream_t stream) {
    const float* CK   = (const float*)d_in[0];
    const float* Win  = (const float*)d_in[1];
    const float* bin  = (const float*)d_in[2];
    const float* Whid = (const float*)d_in[3];
    const float* bhid = (const float*)d_in[4];
    const float* Wout = (const float*)d_in[5];
    const float* bout = (const float*)d_in[6];
    const int* coo    = (const int*)d_in[7];
    float* out        = (float*)d_out;
    float* vals       = (float*)d_ws;

    if (ws_size >= (size_t)WS_NEEDED) {
        int* cnt  = (int*)((char*)d_ws + VALS_B);
        int* bins = (int*)((char*)d_ws + VALS_B + CNT_B);
        zero_cnt<<<(NN + BLK - 1) / BLK, BLK, 0, stream>>>(cnt);
        mlp_bin<<<MLPGRID, BLK, 0, stream>>>(
            CK, Win, bin, Whid, bhid, Wout, bout, coo, vals, cnt, bins, 1);
        fill_merge<<<NN, BLK, 0, stream>>>(vals, coo, cnt, bins, out);
    } else {
        // Fallback (small ws): R9 structure — memset + mlp + atomic scatter.
        hipMemsetAsync(out, 0, OUTBYTES, stream);
        mlp_bin<<<MLPGRID, BLK, 0, stream>>>(
            CK, Win, bin, Whid, bhid, Wout, bout, coo, vals, nullptr, nullptr, 0);
        scatter_add<<<SCGRID, BLK, 0, stream>>>(vals, coo, out);
    }
}